// Round 3
// baseline (1360.717 us; speedup 1.0000x reference)
//
#include <hip/hip_runtime.h>
#include <hip/hip_bf16.h>
#include <math.h>

// Problem constants (fixed by reference file)
#define NN   100000   // nodes
#define NE   640000   // edges
#define DIN  128      // in_channels
#define DO   128      // out_channels (H*C)
#define ED   256      // edge dim (MSG + TD)
#define MSGD 128

typedef __attribute__((ext_vector_type(8))) short s16x8;           // 8 bf16 (A/B frag)
typedef __attribute__((ext_vector_type(4))) float f32x4;           // C/D frag
typedef __attribute__((ext_vector_type(2))) unsigned short u16x2;
typedef __attribute__((ext_vector_type(4))) unsigned short u16x4;
typedef __attribute__((ext_vector_type(8))) unsigned short u16x8;

__device__ __forceinline__ unsigned short f2bs(float f) {
    __hip_bfloat16 h = __float2bfloat16(f);   // RNE
    return __builtin_bit_cast(unsigned short, h);
}
__device__ __forceinline__ float bs2f(unsigned short u) {
    return __uint_as_float(((unsigned int)u) << 16);
}
__device__ __forceinline__ float fast_cos(float x) {
    float rev = x * 0.15915494309189535f;   // 1/(2pi)
    rev = rev - rintf(rev);                 // revolutions, range-reduced
    return __builtin_amdgcn_cosf(rev);
}

// ---------------------------------------------------------------------------
// Kernel 0: weight transposes to bf16 (tiny). WT[n][k] = bf16(W[k][n]).
// ---------------------------------------------------------------------------
__global__ __launch_bounds__(256) void convertW_kernel(
    const float* __restrict__ We, const float* __restrict__ Wq,
    const float* __restrict__ Wk, const float* __restrict__ Wv,
    const float* __restrict__ Ws,
    unsigned short* __restrict__ WeT, unsigned short* __restrict__ WqT,
    unsigned short* __restrict__ WkT, unsigned short* __restrict__ WvT,
    unsigned short* __restrict__ WsT)
{
    const int T0 = ED * DO;                 // 32768 (WeT)
    const int TOT = T0 + 4 * DIN * DO;      // + 4 node mats
    int i = blockIdx.x * 256 + threadIdx.x;
    if (i >= TOT) return;
    if (i < T0) {
        int n = i >> 8, k = i & 255;
        WeT[i] = f2bs(We[(size_t)k * DO + n]);
    } else {
        int j = i - T0; int m = j >> 14; int r = j & 16383;
        int n = r >> 7, k = r & 127;
        const float* W = (m == 0) ? Wq : (m == 1) ? Wk : (m == 2) ? Wv : Ws;
        unsigned short* WD = (m == 0) ? WqT : (m == 1) ? WkT : (m == 2) ? WvT : WsT;
        WD[r] = f2bs(W[(size_t)k * DO + n]);
    }
}

// ---------------------------------------------------------------------------
// Kernel 1: node projections via MFMA. 64 nodes/block, 256 threads (4 waves).
// Reads x fp32 directly (converts in LDS staging). Outputs staged through LDS
// so global stores are fully coalesced (u16x8 / float4).
// ---------------------------------------------------------------------------
__global__ __launch_bounds__(256) void node_proj_kernel(
    const float* __restrict__ x,
    const unsigned short* __restrict__ WqT, const float* __restrict__ bq,
    const unsigned short* __restrict__ WkT, const float* __restrict__ bk,
    const unsigned short* __restrict__ WvT, const float* __restrict__ bv,
    const unsigned short* __restrict__ WsT, const float* __restrict__ bs,
    unsigned short* __restrict__ Qb, unsigned short* __restrict__ Kb,
    unsigned short* __restrict__ Vb, float* __restrict__ SKIP)
{
    __shared__ char smem[64 * 544];   // 34,816B; xt(64x272B), reused for staging
    const int tid = threadIdx.x;
    const int n0  = blockIdx.x * 64;
    unsigned short* xt = (unsigned short*)smem;   // rows: 136 u16 (272B, 16B-mult)

    // stage x -> bf16 in LDS (coalesced float4 reads)
    const float4* x4 = (const float4*)x;
    #pragma unroll
    for (int i = 0; i < 8; ++i) {
        int id = i * 256 + tid; int row = id >> 5, c4 = id & 31;
        int gn = n0 + row; if (gn > NN - 1) gn = NN - 1;
        float4 v = x4[(size_t)gn * 32 + c4];
        u16x4 b; b.x = f2bs(v.x); b.y = f2bs(v.y); b.z = f2bs(v.z); b.w = f2bs(v.w);
        *(u16x4*)(xt + row * 136 + c4 * 4) = b;
    }
    __syncthreads();

    const int lane = tid & 63, w = tid >> 6;
    const int l15 = lane & 15, quad = lane >> 4;

    // load A-fragments into registers, then LDS is free for reuse
    s16x8 afrag[4];
    {
        const unsigned short* arow = xt + (w * 16 + l15) * 136 + quad * 8;
        #pragma unroll
        for (int ks = 0; ks < 4; ++ks) afrag[ks] = *(const s16x8*)(arow + ks * 32);
    }
    __syncthreads();

    const unsigned short* WT[4] = {WqT, WkT, WvT, WsT};
    const float*          BI[4] = {bq, bk, bv, bs};
    unsigned short*       OB[3] = {Qb, Kb, Vb};

    #pragma unroll
    for (int m = 0; m < 4; ++m) {
        f32x4 acc[8];
        #pragma unroll
        for (int j = 0; j < 8; ++j) { float b = BI[m][j * 16 + l15]; acc[j] = {b, b, b, b}; }
        const unsigned short* Wm = WT[m];
        #pragma unroll
        for (int ks = 0; ks < 4; ++ks) {
            #pragma unroll
            for (int j = 0; j < 8; ++j) {
                s16x8 bf = *(const s16x8*)(Wm + (j * 16 + l15) * DIN + ks * 32 + quad * 8);
                acc[j] = __builtin_amdgcn_mfma_f32_16x16x32_bf16(afrag[ks], bf, acc[j], 0, 0, 0);
            }
        }
        if (m < 3) {
            unsigned short* sb = (unsigned short*)smem;   // rows: 136 u16
            #pragma unroll
            for (int j = 0; j < 8; ++j)
                #pragma unroll
                for (int r = 0; r < 4; ++r)
                    sb[(w * 16 + quad * 4 + r) * 136 + j * 16 + l15] = f2bs(acc[j][r]);
            __syncthreads();
            unsigned short* Ob = OB[m];
            #pragma unroll
            for (int i = 0; i < 4; ++i) {
                int id = i * 256 + tid; int row = id >> 4, c8 = id & 15;
                if (n0 + row < NN)
                    *(u16x8*)(Ob + (size_t)(n0 + row) * DO + c8 * 8) =
                        *(u16x8*)(sb + row * 136 + c8 * 8);
            }
            __syncthreads();
        } else {
            float* sf = (float*)smem;                     // rows: 136 f32 (544B)
            #pragma unroll
            for (int j = 0; j < 8; ++j)
                #pragma unroll
                for (int r = 0; r < 4; ++r)
                    sf[(w * 16 + quad * 4 + r) * 136 + j * 16 + l15] = acc[j][r];
            __syncthreads();
            #pragma unroll
            for (int i = 0; i < 8; ++i) {
                int id = i * 256 + tid; int row = id >> 5, c4 = id & 31;
                if (n0 + row < NN)
                    *(float4*)(SKIP + (size_t)(n0 + row) * DO + c4 * 4) =
                        *(float4*)(sf + row * 136 + c4 * 4);
            }
        }
    }
}

// ---------------------------------------------------------------------------
// Sort-by-dst kernels: histogram -> single-block scan -> scatter
// ---------------------------------------------------------------------------
__global__ __launch_bounds__(256) void hist_kernel(
    const int* __restrict__ dstI, int* __restrict__ COUNT)
{
    int e = blockIdx.x * 256 + threadIdx.x;
    if (e < NE) atomicAdd(&COUNT[dstI[e]], 1);
}

__global__ __launch_bounds__(1024) void scan_kernel(
    const int* __restrict__ COUNT, int* __restrict__ OFFS, int* __restrict__ CUR)
{
    __shared__ int part[1024];
    const int t = threadIdx.x;
    const int CH = (NN + 1023) / 1024;    // 98
    const int base = t * CH;
    int s = 0;
    for (int i = 0; i < CH; ++i) { int idx = base + i; if (idx < NN) s += COUNT[idx]; }
    part[t] = s;
    __syncthreads();
    for (int off = 1; off < 1024; off <<= 1) {
        int v = (t >= off) ? part[t - off] : 0;
        __syncthreads();
        part[t] += v;
        __syncthreads();
    }
    int excl = (t == 0) ? 0 : part[t - 1];
    for (int i = 0; i < CH; ++i) {
        int idx = base + i;
        if (idx < NN) { OFFS[idx] = excl; CUR[idx] = excl; excl += COUNT[idx]; }
    }
    if (t == 1023) OFFS[NN] = part[1023];
}

__global__ __launch_bounds__(256) void scatter_kernel(
    const int* __restrict__ dstI, int* __restrict__ CUR, int* __restrict__ SORT)
{
    int e = blockIdx.x * 256 + threadIdx.x;
    if (e < NE) {
        int p = atomicAdd(&CUR[dstI[e]], 1);
        SORT[p] = e;
    }
}

// ---------------------------------------------------------------------------
// Pass A: edge GEMM. 64 edges/block, 256 threads (4 waves).
// attr (bf16) staged in LDS -> e = attr @ We via MFMA -> e written back into
// the same LDS buffer -> KE = bf16(k[src]+e), VE = bf16(v[src]+e) stored
// coalesced. No shuffles, no atomics.
// ---------------------------------------------------------------------------
__global__ __launch_bounds__(256) void edge_gemm_kernel(
    const float* __restrict__ last_update, const float* __restrict__ tarr,
    const float* __restrict__ msg,
    const float* __restrict__ w_time, const float* __restrict__ b_time,
    const unsigned short* __restrict__ WeT,
    const int* __restrict__ srcI,
    const unsigned short* __restrict__ Kb, const unsigned short* __restrict__ Vb,
    unsigned short* __restrict__ KEb, unsigned short* __restrict__ VEb)
{
    __shared__ char smem[64 * 528];  // attr rows: 264 u16 (528B); reused for e rows: 132 u16
    __shared__ int   ssrc[64];
    __shared__ float srel[64];
    const int tid = threadIdx.x;
    const int e0  = blockIdx.x * 64;

    if (tid < 64) {
        int s = srcI[e0 + tid];
        ssrc[tid] = s;
        srel[tid] = last_update[s] - tarr[e0 + tid];
    }
    __syncthreads();

    unsigned short* at = (unsigned short*)smem;
    const float4* msg4 = (const float4*)msg;
    #pragma unroll
    for (int i = 0; i < 8; ++i) {
        int q = i * 256 + tid; int e = q >> 5, c4 = q & 31;
        float4 m4 = msg4[(size_t)(e0 + e) * 32 + c4];
        u16x4 b; b.x = f2bs(m4.x); b.y = f2bs(m4.y); b.z = f2bs(m4.z); b.w = f2bs(m4.w);
        *(u16x4*)(at + e * 264 + c4 * 4) = b;
    }
    #pragma unroll
    for (int i = 0; i < 32; ++i) {
        int q = i * 256 + tid; int e = q >> 7, j = q & 127;
        float v = fast_cos(srel[e] * w_time[j] + b_time[j]);
        at[e * 264 + MSGD + j] = f2bs(v);
    }
    __syncthreads();

    const int lane = tid & 63, w = tid >> 6;
    const int l15 = lane & 15, quad = lane >> 4;

    f32x4 acc[8];
    #pragma unroll
    for (int j = 0; j < 8; ++j) acc[j] = {0.f, 0.f, 0.f, 0.f};
    const unsigned short* arow = at + (w * 16 + l15) * 264 + quad * 8;
    #pragma unroll
    for (int ks = 0; ks < 8; ++ks) {
        s16x8 a = *(const s16x8*)(arow + ks * 32);
        #pragma unroll
        for (int j = 0; j < 8; ++j) {
            s16x8 b = *(const s16x8*)(WeT + (j * 16 + l15) * ED + ks * 32 + quad * 8);
            acc[j] = __builtin_amdgcn_mfma_f32_16x16x32_bf16(a, b, acc[j], 0, 0, 0);
        }
    }
    __syncthreads();   // attr consumed; reuse buffer for e (bf16 rows of 132 u16)

    unsigned short* eb = (unsigned short*)smem;
    #pragma unroll
    for (int j = 0; j < 8; ++j)
        #pragma unroll
        for (int r = 0; r < 4; ++r)
            eb[(w * 16 + quad * 4 + r) * 132 + j * 16 + l15] = f2bs(acc[j][r]);
    __syncthreads();

    const int c = tid & 127;
    const int g = tid >> 7;
    #pragma unroll 4
    for (int i = 0; i < 32; ++i) {
        int e = g * 32 + i;
        int s = ssrc[e];
        float ef = bs2f(eb[e * 132 + c]);
        float kv = bs2f(Kb[(size_t)s * DO + c]);
        float vv = bs2f(Vb[(size_t)s * DO + c]);
        KEb[(size_t)(e0 + e) * DO + c] = f2bs(kv + ef);
        VEb[(size_t)(e0 + e) * DO + c] = f2bs(vv + ef);
    }
}

// ---------------------------------------------------------------------------
// Pass B: per-node attention. One wave per dst node, 4 waves/block, no LDS.
// Lane l handles cols 2l, 2l+1 (head = l>>5). Walks sorted edge list with
// coalesced 256B row loads; softmax without segment-max (|alpha| small);
// single non-atomic coalesced output write fused with skip.
// ---------------------------------------------------------------------------
__global__ __launch_bounds__(256) void node_attn_kernel(
    const int* __restrict__ OFFS, const int* __restrict__ SORT,
    const unsigned short* __restrict__ Qb,
    const unsigned short* __restrict__ KEb, const unsigned short* __restrict__ VEb,
    const float* __restrict__ SKIP, float* __restrict__ out)
{
    const int w = threadIdx.x >> 6, lane = threadIdx.x & 63;
    const int n = blockIdx.x * 4 + w;          // grid 25000 -> exactly NN waves
    const int beg = OFFS[n], end = OFFS[n + 1];

    u16x2 qv = *(const u16x2*)(Qb + (size_t)n * DO + lane * 2);
    float q0 = bs2f(qv.x), q1 = bs2f(qv.y);

    float acc0 = 0.f, acc1 = 0.f, den = 0.f;
    for (int j = beg; j < end; ++j) {
        int e = SORT[j];
        u16x2 ke = *(const u16x2*)(KEb + (size_t)e * DO + lane * 2);
        u16x2 ve = *(const u16x2*)(VEb + (size_t)e * DO + lane * 2);
        float p = q0 * bs2f(ke.x) + q1 * bs2f(ke.y);
        #pragma unroll
        for (int off = 16; off; off >>= 1) p += __shfl_xor(p, off, 64);  // reduce within 32-lane head
        float ea = __expf(p * 0.125f);         // / sqrt(C=64)
        den  += ea;
        acc0 += ea * bs2f(ve.x);
        acc1 += ea * bs2f(ve.y);
    }
    float inv = 1.0f / (den + 1e-16f);
    float2 sk = *(const float2*)(SKIP + (size_t)n * DO + lane * 2);
    float2 o; o.x = acc0 * inv + sk.x; o.y = acc1 * inv + sk.y;
    *(float2*)(out + (size_t)n * DO + lane * 2) = o;
}

extern "C" void kernel_launch(void* const* d_in, const int* in_sizes, int n_in,
                              void* d_out, int out_size, void* d_ws, size_t ws_size,
                              hipStream_t stream) {
    const float* x           = (const float*)d_in[0];
    const float* last_update = (const float*)d_in[1];
    const float* tarr        = (const float*)d_in[2];
    const float* msg         = (const float*)d_in[3];
    const float* w_time      = (const float*)d_in[4];
    const float* b_time      = (const float*)d_in[5];
    const float* Wq          = (const float*)d_in[6];
    const float* bq          = (const float*)d_in[7];
    const float* Wk          = (const float*)d_in[8];
    const float* bk          = (const float*)d_in[9];
    const float* Wv          = (const float*)d_in[10];
    const float* bv          = (const float*)d_in[11];
    const float* We          = (const float*)d_in[12];
    const float* Ws          = (const float*)d_in[13];
    const float* bs          = (const float*)d_in[14];
    const int*   ei          = (const int*)d_in[15];
    const int*   srcI = ei;
    const int*   dstI = ei + NE;

    float* out = (float*)d_out;
    char*  ws  = (char*)d_ws;
    // byte layout (16B-aligned)
    unsigned short* Qb  = (unsigned short*)(ws);                    //  25,600,000
    unsigned short* Kb  = (unsigned short*)(ws +  25600000);        //  25,600,000
    unsigned short* Vb  = (unsigned short*)(ws +  51200000);        //  25,600,000
    float*          SKIP= (float*)         (ws +  76800000);        //  51,200,000
    unsigned short* KEb = (unsigned short*)(ws + 128000000);        // 163,840,000
    unsigned short* VEb = (unsigned short*)(ws + 291840000);        // 163,840,000
    unsigned short* WeT = (unsigned short*)(ws + 455680000);        //      65,536
    unsigned short* WqT = (unsigned short*)(ws + 455745536);        //      32,768
    unsigned short* WkT = (unsigned short*)(ws + 455778304);        //      32,768
    unsigned short* WvT = (unsigned short*)(ws + 455811072);        //      32,768
    unsigned short* WsT = (unsigned short*)(ws + 455843840);        //      32,768
    int*            COUNT=(int*)           (ws + 455876608);        //     400,000
    int*            OFFS= (int*)           (ws + 456276608);        //     400,016
    int*            CUR = (int*)           (ws + 456676624);        //     400,000
    int*            SORT= (int*)           (ws + 457076624);        //   2,560,000

    hipMemsetAsync(COUNT, 0, (size_t)NN * sizeof(int), stream);

    convertW_kernel<<<(ED * DO + 4 * DIN * DO + 255) / 256, 256, 0, stream>>>(
        We, Wq, Wk, Wv, Ws, WeT, WqT, WkT, WvT, WsT);

    node_proj_kernel<<<(NN + 63) / 64, 256, 0, stream>>>(
        x, WqT, bq, WkT, bk, WvT, bv, WsT, bs, Qb, Kb, Vb, SKIP);

    hist_kernel<<<(NE + 255) / 256, 256, 0, stream>>>(dstI, COUNT);
    scan_kernel<<<1, 1024, 0, stream>>>(COUNT, OFFS, CUR);
    scatter_kernel<<<(NE + 255) / 256, 256, 0, stream>>>(dstI, CUR, SORT);

    edge_gemm_kernel<<<NE / 64, 256, 0, stream>>>(
        last_update, tarr, msg, w_time, b_time, WeT, srcI, Kb, Vb, KEb, VEb);

    node_attn_kernel<<<NN / 4, 256, 0, stream>>>(
        OFFS, SORT, Qb, KEb, VEb, SKIP, out);
}